// Round 1
// baseline (228.889 us; speedup 1.0000x reference)
//
#include <hip/hip_runtime.h>
#include <hip/hip_bf16.h>

#define HEADS 16
#define DH 64
#define DIM 1024
#define SEQ 2048
#define BATCH 2
#define ROWS (BATCH*SEQ)      // 4096
#define NQKV (3*DIM)          // 3072

typedef __attribute__((ext_vector_type(8))) short bf16x8;
typedef __attribute__((ext_vector_type(4))) float f32x4;
typedef __hip_bfloat16 bf16;

static __device__ __forceinline__ bf16 f2bf(float v){ return __float2bfloat16(v); }

static __device__ __forceinline__ void gload16(const void* g, void* lds){
  __builtin_amdgcn_global_load_lds((const __attribute__((address_space(1))) void*)g,
                                   (__attribute__((address_space(3))) void*)lds, 16, 0, 0);
}

// ---------------- LayerNorm: fp32 in -> bf16 out ----------------
__global__ __launch_bounds__(256) void ln_kernel(const float* __restrict__ x,
    const float* __restrict__ gamma, const float* __restrict__ beta,
    bf16* __restrict__ xn)
{
  int row = blockIdx.x;
  int tid = threadIdx.x;
  float4 v = ((const float4*)(x + (size_t)row*DIM))[tid];
  float s  = v.x+v.y+v.z+v.w;
  float ss = v.x*v.x+v.y*v.y+v.z*v.z+v.w*v.w;
  #pragma unroll
  for (int m=1;m<64;m<<=1){ s += __shfl_xor(s,m); ss += __shfl_xor(ss,m); }
  __shared__ float red[8];
  int wid = tid>>6;
  if ((tid&63)==0){ red[wid]=s; red[4+wid]=ss; }
  __syncthreads();
  s  = red[0]+red[1]+red[2]+red[3];
  ss = red[4]+red[5]+red[6]+red[7];
  float mu  = s*(1.0f/DIM);
  float var = ss*(1.0f/DIM) - mu*mu;
  float inv = rsqrtf(var + 1e-5f);
  float4 g  = ((const float4*)gamma)[tid];
  float4 bb = ((const float4*)beta)[tid];
  __align__(8) bf16 o[4];
  o[0]=f2bf((v.x-mu)*inv*g.x+bb.x);
  o[1]=f2bf((v.y-mu)*inv*g.y+bb.y);
  o[2]=f2bf((v.z-mu)*inv*g.z+bb.z);
  o[3]=f2bf((v.w-mu)*inv*g.w+bb.w);
  *(uint2*)&xn[(size_t)row*DIM + tid*4] = *(const uint2*)o;
}

// ---------------- transpose + cast: in[R][C] fp32 -> out[C][R] bf16 ----------------
__global__ __launch_bounds__(256) void transpose_cast(const float* __restrict__ in,
    bf16* __restrict__ out, int R, int C)
{
  __shared__ __align__(16) bf16 t[64][72];
  int c0 = blockIdx.x*64, r0 = blockIdx.y*64;
  int tid = threadIdx.x;
  int row = tid>>2;
  int cq  = (tid&3)*16;
  #pragma unroll
  for (int j=0;j<4;j++){
    float4 v = *(const float4*)&in[(size_t)(r0+row)*C + c0 + cq + j*4];
    t[cq+j*4+0][row] = f2bf(v.x);
    t[cq+j*4+1][row] = f2bf(v.y);
    t[cq+j*4+2][row] = f2bf(v.z);
    t[cq+j*4+3][row] = f2bf(v.w);
  }
  __syncthreads();
  int c = tid>>2; int rq = (tid&3)*16;
  uint4 u0 = *(const uint4*)&t[c][rq];
  uint4 u1 = *(const uint4*)&t[c][rq+8];
  *(uint4*)&out[(size_t)(c0+c)*R + r0 + rq]     = u0;
  *(uint4*)&out[(size_t)(c0+c)*R + r0 + rq + 8] = u1;
}

// ---------------- GEMM: C[M][N] = A[M][K] * Bt[N][K]^T  (m97 structure) ----------------
// mode 0: epilogue scatters to q (scaled), k ([bh][n][d]) and vt ([bh][d][n]), all bf16
// mode 1: epilogue writes fp32 out + bias
__global__ __launch_bounds__(256) void gemm_bt(
    const bf16* __restrict__ A, const bf16* __restrict__ Bt, int K, int mode,
    bf16* __restrict__ qb, bf16* __restrict__ kb, bf16* __restrict__ vtb,
    float* __restrict__ outf, const float* __restrict__ bias)
{
  __shared__ __align__(16) bf16 aL[128*32];
  __shared__ __align__(16) bf16 bL[128*32];
  int tid = threadIdx.x;
  int w = tid>>6, l = tid&63;
  int lr = l&15, lh = l>>4;
  int wr = w>>1, wc = w&1;
  int by = blockIdx.y, bx = blockIdx.x;
  const bf16* Ab = A  + (size_t)(by*128)*K;
  const bf16* Bb = Bt + (size_t)(bx*128)*K;
  int srow = w*32 + (l>>2);     // + issue*16
  int skc  = (l&3)*8;
  f32x4 acc[4][4] = {};
  for (int k0=0; k0<K; k0+=32){
    gload16(Ab + (size_t)(srow   )*K + k0 + skc, aL + w*1024      );
    gload16(Ab + (size_t)(srow+16)*K + k0 + skc, aL + w*1024 + 512);
    gload16(Bb + (size_t)(srow   )*K + k0 + skc, bL + w*1024      );
    gload16(Bb + (size_t)(srow+16)*K + k0 + skc, bL + w*1024 + 512);
    __syncthreads();
    bf16x8 af[4], bfr[4];
    #pragma unroll
    for (int m=0;m<4;m++) af[m]  = *(const bf16x8*)&aL[(wr*64 + m*16 + lr)*32 + lh*8];
    #pragma unroll
    for (int n=0;n<4;n++) bfr[n] = *(const bf16x8*)&bL[(wc*64 + n*16 + lr)*32 + lh*8];
    #pragma unroll
    for (int m=0;m<4;m++)
      #pragma unroll
      for (int n=0;n<4;n++)
        acc[m][n] = __builtin_amdgcn_mfma_f32_16x16x32_bf16(af[m], bfr[n], acc[m][n], 0,0,0);
    __syncthreads();
  }
  int rb = by*128 + wr*64, cb = bx*128 + wc*64;
  if (mode == 0){
    #pragma unroll
    for (int m=0;m<4;m++)
      #pragma unroll
      for (int n=0;n<4;n++)
        #pragma unroll
        for (int reg=0;reg<4;reg++){
          int r = rb + m*16 + lh*4 + reg;
          int c = cb + n*16 + lr;
          float v = acc[m][n][reg];
          int b = r >> 11, nn = r & 2047;
          int which = c >> 10, rem = c & 1023;
          int hh = rem >> 6, dd = rem & 63;
          int bh = b*HEADS + hh;
          if (which==0)      qb[((size_t)bh*SEQ + nn)*DH + dd] = f2bf(v*0.125f);
          else if (which==1) kb[((size_t)bh*SEQ + nn)*DH + dd] = f2bf(v);
          else               vtb[((size_t)bh*DH + dd)*SEQ + nn] = f2bf(v);
        }
  } else {
    #pragma unroll
    for (int m=0;m<4;m++)
      #pragma unroll
      for (int n=0;n<4;n++)
        #pragma unroll
        for (int reg=0;reg<4;reg++){
          int r = rb + m*16 + lh*4 + reg;
          int c = cb + n*16 + lr;
          outf[(size_t)r*DIM + c] = acc[m][n][reg] + bias[c];
        }
  }
}

// ---------------- flash attention: q[bh][n][d], k[bh][n][d], vt[bh][d][n] -> ao[b][n][h*d] ----------------
__global__ __launch_bounds__(256) void attn_kernel(
    const bf16* __restrict__ qb, const bf16* __restrict__ kb,
    const bf16* __restrict__ vtb, bf16* __restrict__ ao)
{
  __shared__ __align__(16) bf16 pl[4][32][72];   // per-wave P buffer, padded
  int tid = threadIdx.x;
  int w = tid>>6, l = tid&63;
  int lr = l&15, lh = l>>4;
  int bh = blockIdx.y;
  int b  = bh >> 4;
  int hh = bh & 15;
  const bf16* Q  = qb  + (size_t)bh*SEQ*DH;
  const bf16* Kp = kb  + (size_t)bh*SEQ*DH;
  const bf16* Vt = vtb + (size_t)bh*DH*SEQ;
  int q0 = blockIdx.x*128 + w*32;   // this wave's 32 Q rows

  bf16x8 qf[2][2];
  #pragma unroll
  for (int m=0;m<2;m++)
    #pragma unroll
    for (int kd=0;kd<2;kd++)
      qf[m][kd] = *(const bf16x8*)&Q[(size_t)(q0 + m*16 + lr)*DH + kd*32 + lh*8];

  f32x4 o[2][4] = {};
  float mrun[2][4], lrun[2][4];
  #pragma unroll
  for (int m=0;m<2;m++)
    #pragma unroll
    for (int r=0;r<4;r++){ mrun[m][r] = -3e38f; lrun[m][r] = 0.f; }

  for (int kv0=0; kv0<SEQ; kv0+=64){
    // S = Q K^T  (rows = Q rows, cols = kv)
    f32x4 s[2][4] = {};
    #pragma unroll
    for (int kd=0;kd<2;kd++){
      bf16x8 kf[4];
      #pragma unroll
      for (int n=0;n<4;n++)
        kf[n] = *(const bf16x8*)&Kp[(size_t)(kv0 + n*16 + lr)*DH + kd*32 + lh*8];
      #pragma unroll
      for (int m=0;m<2;m++)
        #pragma unroll
        for (int n=0;n<4;n++)
          s[m][n] = __builtin_amdgcn_mfma_f32_16x16x32_bf16(qf[m][kd], kf[n], s[m][n], 0,0,0);
    }
    // online softmax (fp32), rows distributed as row = m*16 + lh*4 + reg, col = n*16 + lr
    #pragma unroll
    for (int m=0;m<2;m++){
      float tm[4];
      #pragma unroll
      for (int reg=0;reg<4;reg++)
        tm[reg] = fmaxf(fmaxf(s[m][0][reg], s[m][1][reg]), fmaxf(s[m][2][reg], s[m][3][reg]));
      #pragma unroll
      for (int msk=1; msk<16; msk<<=1)
        #pragma unroll
        for (int reg=0;reg<4;reg++)
          tm[reg] = fmaxf(tm[reg], __shfl_xor(tm[reg], msk));
      float rs[4];
      #pragma unroll
      for (int reg=0;reg<4;reg++){
        float mn = fmaxf(mrun[m][reg], tm[reg]);
        float sc = __expf(mrun[m][reg] - mn);
        mrun[m][reg] = mn;
        lrun[m][reg] *= sc;
        #pragma unroll
        for (int n=0;n<4;n++) o[m][n][reg] *= sc;
        rs[reg] = 0.f;
        #pragma unroll
        for (int n=0;n<4;n++){
          float p = __expf(s[m][n][reg] - mn);
          s[m][n][reg] = p;
          rs[reg] += p;
        }
      }
      #pragma unroll
      for (int msk=1; msk<16; msk<<=1)
        #pragma unroll
        for (int reg=0;reg<4;reg++)
          rs[reg] += __shfl_xor(rs[reg], msk);
      #pragma unroll
      for (int reg=0;reg<4;reg++) lrun[m][reg] += rs[reg];
      // P -> LDS (bf16), transposing register layout to A-frag layout
      #pragma unroll
      for (int n=0;n<4;n++)
        #pragma unroll
        for (int reg=0;reg<4;reg++)
          pl[w][m*16 + lh*4 + reg][n*16 + lr] = f2bf(s[m][n][reg]);
    }
    // O += P @ V   (A = P [32][64], B = Vt [d][kv])
    #pragma unroll
    for (int kk=0;kk<2;kk++){
      bf16x8 pf[2], vf[4];
      #pragma unroll
      for (int m=0;m<2;m++)
        pf[m] = *(const bf16x8*)&pl[w][m*16 + lr][kk*32 + lh*8];
      #pragma unroll
      for (int n=0;n<4;n++)
        vf[n] = *(const bf16x8*)&Vt[(size_t)(n*16 + lr)*SEQ + kv0 + kk*32 + lh*8];
      #pragma unroll
      for (int m=0;m<2;m++)
        #pragma unroll
        for (int n=0;n<4;n++)
          o[m][n] = __builtin_amdgcn_mfma_f32_16x16x32_bf16(pf[m], vf[n], o[m][n], 0,0,0);
    }
  }
  // epilogue: normalize, store to ao[b][n][h*64+d]
  #pragma unroll
  for (int m=0;m<2;m++)
    #pragma unroll
    for (int n=0;n<4;n++)
      #pragma unroll
      for (int reg=0;reg<4;reg++){
        int r = q0 + m*16 + lh*4 + reg;
        int c = hh*DH + n*16 + lr;
        ao[((size_t)b*SEQ + r)*DIM + c] = f2bf(o[m][n][reg] / lrun[m][reg]);
      }
}

extern "C" void kernel_launch(void* const* d_in, const int* in_sizes, int n_in,
                              void* d_out, int out_size, void* d_ws, size_t ws_size,
                              hipStream_t stream)
{
  const float* x     = (const float*)d_in[0];
  const float* gamma = (const float*)d_in[1];
  const float* beta  = (const float*)d_in[2];
  const float* w_qkv = (const float*)d_in[3];
  const float* w_out = (const float*)d_in[4];
  const float* b_out = (const float*)d_in[5];
  float* out = (float*)d_out;

  bf16* ws  = (bf16*)d_ws;
  bf16* xn  = ws;                                  // 4096*1024
  bf16* wqt = xn  + (size_t)ROWS*DIM;              // 3072*1024
  bf16* wot = wqt + (size_t)NQKV*DIM;              // 1024*1024
  bf16* qb  = wot + (size_t)DIM*DIM;               // 32*2048*64
  bf16* kb  = qb  + (size_t)BATCH*HEADS*SEQ*DH;
  bf16* vtb = kb  + (size_t)BATCH*HEADS*SEQ*DH;
  bf16* ao  = vtb + (size_t)BATCH*HEADS*SEQ*DH;    // 4096*1024

  hipLaunchKernelGGL(ln_kernel, dim3(ROWS), dim3(256), 0, stream, x, gamma, beta, xn);
  hipLaunchKernelGGL(transpose_cast, dim3(NQKV/64, DIM/64), dim3(256), 0, stream, w_qkv, wqt, DIM, NQKV);
  hipLaunchKernelGGL(transpose_cast, dim3(DIM/64,  DIM/64), dim3(256), 0, stream, w_out, wot, DIM, DIM);
  hipLaunchKernelGGL(gemm_bt, dim3(NQKV/128, ROWS/128), dim3(256), 0, stream,
                     xn, wqt, DIM, 0, qb, kb, vtb, (float*)nullptr, (const float*)nullptr);
  hipLaunchKernelGGL(attn_kernel, dim3(SEQ/128, BATCH*HEADS), dim3(256), 0, stream, qb, kb, vtb, ao);
  hipLaunchKernelGGL(gemm_bt, dim3(DIM/128, ROWS/128), dim3(256), 0, stream,
                     ao, wot, DIM, 1, (bf16*)nullptr, (bf16*)nullptr, (bf16*)nullptr, out, b_out);
}

// Round 2
// 209.069 us; speedup vs baseline: 1.0948x; 1.0948x over previous
//
#include <hip/hip_runtime.h>
#include <hip/hip_bf16.h>

#define HEADS 16
#define DH 64
#define DIM 1024
#define SEQ 2048
#define BATCH 2
#define ROWS (BATCH*SEQ)      // 4096
#define NQKV (3*DIM)          // 3072

typedef __attribute__((ext_vector_type(8))) short bf16x8;
typedef __attribute__((ext_vector_type(4))) float f32x4;
typedef __hip_bfloat16 bf16;

static __device__ __forceinline__ bf16 f2bf(float v){ return __float2bfloat16(v); }

static __device__ __forceinline__ unsigned pack2bf(float a, float b){
  bf16 x = f2bf(a), y = f2bf(b);
  unsigned short ux = *(unsigned short*)&x, uy = *(unsigned short*)&y;
  return (unsigned)ux | ((unsigned)uy << 16);
}

static __device__ __forceinline__ void gload16(const void* g, void* lds){
  __builtin_amdgcn_global_load_lds((const __attribute__((address_space(1))) void*)g,
                                   (__attribute__((address_space(3))) void*)lds, 16, 0, 0);
}

// ---------------- LayerNorm: fp32 in -> bf16 out ----------------
__global__ __launch_bounds__(256) void ln_kernel(const float* __restrict__ x,
    const float* __restrict__ gamma, const float* __restrict__ beta,
    bf16* __restrict__ xn)
{
  int row = blockIdx.x;
  int tid = threadIdx.x;
  float4 v = ((const float4*)(x + (size_t)row*DIM))[tid];
  float s  = v.x+v.y+v.z+v.w;
  float ss = v.x*v.x+v.y*v.y+v.z*v.z+v.w*v.w;
  #pragma unroll
  for (int m=1;m<64;m<<=1){ s += __shfl_xor(s,m); ss += __shfl_xor(ss,m); }
  __shared__ float red[8];
  int wid = tid>>6;
  if ((tid&63)==0){ red[wid]=s; red[4+wid]=ss; }
  __syncthreads();
  s  = red[0]+red[1]+red[2]+red[3];
  ss = red[4]+red[5]+red[6]+red[7];
  float mu  = s*(1.0f/DIM);
  float var = ss*(1.0f/DIM) - mu*mu;
  float inv = rsqrtf(var + 1e-5f);
  float4 g  = ((const float4*)gamma)[tid];
  float4 bb = ((const float4*)beta)[tid];
  __align__(8) bf16 o[4];
  o[0]=f2bf((v.x-mu)*inv*g.x+bb.x);
  o[1]=f2bf((v.y-mu)*inv*g.y+bb.y);
  o[2]=f2bf((v.z-mu)*inv*g.z+bb.z);
  o[3]=f2bf((v.w-mu)*inv*g.w+bb.w);
  *(uint2*)&xn[(size_t)row*DIM + tid*4] = *(const uint2*)o;
}

// ---------------- transpose + cast: in[R][C] fp32 -> out[C][R] bf16 ----------------
__global__ __launch_bounds__(256) void transpose_cast(const float* __restrict__ in,
    bf16* __restrict__ out, int R, int C)
{
  __shared__ __align__(16) bf16 t[64][72];
  int c0 = blockIdx.x*64, r0 = blockIdx.y*64;
  int tid = threadIdx.x;
  int row = tid>>2;
  int cq  = (tid&3)*16;
  #pragma unroll
  for (int j=0;j<4;j++){
    float4 v = *(const float4*)&in[(size_t)(r0+row)*C + c0 + cq + j*4];
    t[cq+j*4+0][row] = f2bf(v.x);
    t[cq+j*4+1][row] = f2bf(v.y);
    t[cq+j*4+2][row] = f2bf(v.z);
    t[cq+j*4+3][row] = f2bf(v.w);
  }
  __syncthreads();
  int c = tid>>2; int rq = (tid&3)*16;
  uint4 u0 = *(const uint4*)&t[c][rq];
  uint4 u1 = *(const uint4*)&t[c][rq+8];
  *(uint4*)&out[(size_t)(c0+c)*R + r0 + rq]     = u0;
  *(uint4*)&out[(size_t)(c0+c)*R + r0 + rq + 8] = u1;
}

// ---------------- GEMM: C[M][N] = A[M][K] * Bt[N][K]^T  (m97 structure) ----------------
__global__ __launch_bounds__(256) void gemm_bt(
    const bf16* __restrict__ A, const bf16* __restrict__ Bt, int K, int mode,
    bf16* __restrict__ qb, bf16* __restrict__ kb, bf16* __restrict__ vtb,
    float* __restrict__ outf, const float* __restrict__ bias)
{
  __shared__ __align__(16) bf16 aL[128*32];
  __shared__ __align__(16) bf16 bL[128*32];
  int tid = threadIdx.x;
  int w = tid>>6, l = tid&63;
  int lr = l&15, lh = l>>4;
  int wr = w>>1, wc = w&1;
  int by = blockIdx.y, bx = blockIdx.x;
  const bf16* Ab = A  + (size_t)(by*128)*K;
  const bf16* Bb = Bt + (size_t)(bx*128)*K;
  int srow = w*32 + (l>>2);
  int skc  = (l&3)*8;
  f32x4 acc[4][4] = {};
  for (int k0=0; k0<K; k0+=32){
    gload16(Ab + (size_t)(srow   )*K + k0 + skc, aL + w*1024      );
    gload16(Ab + (size_t)(srow+16)*K + k0 + skc, aL + w*1024 + 512);
    gload16(Bb + (size_t)(srow   )*K + k0 + skc, bL + w*1024      );
    gload16(Bb + (size_t)(srow+16)*K + k0 + skc, bL + w*1024 + 512);
    __syncthreads();
    bf16x8 af[4], bfr[4];
    #pragma unroll
    for (int m=0;m<4;m++) af[m]  = *(const bf16x8*)&aL[(wr*64 + m*16 + lr)*32 + lh*8];
    #pragma unroll
    for (int n=0;n<4;n++) bfr[n] = *(const bf16x8*)&bL[(wc*64 + n*16 + lr)*32 + lh*8];
    #pragma unroll
    for (int m=0;m<4;m++)
      #pragma unroll
      for (int n=0;n<4;n++)
        acc[m][n] = __builtin_amdgcn_mfma_f32_16x16x32_bf16(af[m], bfr[n], acc[m][n], 0,0,0);
    __syncthreads();
  }
  int rb = by*128 + wr*64, cb = bx*128 + wc*64;
  if (mode == 0){
    #pragma unroll
    for (int m=0;m<4;m++)
      #pragma unroll
      for (int n=0;n<4;n++)
        #pragma unroll
        for (int reg=0;reg<4;reg++){
          int r = rb + m*16 + lh*4 + reg;
          int c = cb + n*16 + lr;
          float v = acc[m][n][reg];
          int b = r >> 11, nn = r & 2047;
          int which = c >> 10, rem = c & 1023;
          int hh = rem >> 6, dd = rem & 63;
          int bh = b*HEADS + hh;
          if (which==0)      qb[((size_t)bh*SEQ + nn)*DH + dd] = f2bf(v*0.125f);
          else if (which==1) kb[((size_t)bh*SEQ + nn)*DH + dd] = f2bf(v);
          else               vtb[((size_t)bh*DH + dd)*SEQ + nn] = f2bf(v);
        }
  } else {
    #pragma unroll
    for (int m=0;m<4;m++)
      #pragma unroll
      for (int n=0;n<4;n++)
        #pragma unroll
        for (int reg=0;reg<4;reg++){
          int r = rb + m*16 + lh*4 + reg;
          int c = cb + n*16 + lr;
          outf[(size_t)r*DIM + c] = acc[m][n][reg] + bias[c];
        }
  }
}

// ---------------- flash attention v2: swapped QK^T, in-lane softmax, K/V reg prefetch ----
__global__ __launch_bounds__(256,2) void attn_kernel(
    const bf16* __restrict__ qb, const bf16* __restrict__ kb,
    const bf16* __restrict__ vtb, bf16* __restrict__ ao)
{
  __shared__ __align__(16) bf16 pl[4][32][72];   // per-wave P, 144B row stride (16B-aligned)
  int tid = threadIdx.x;
  int w = tid>>6, l = tid&63;
  int lr = l&15, lh = l>>4;
  int bh = blockIdx.y;
  int b  = bh >> 4;
  int hh = bh & 15;
  const bf16* Q  = qb  + (size_t)bh*SEQ*DH;
  const bf16* Kp = kb  + (size_t)bh*SEQ*DH;
  const bf16* Vt = vtb + (size_t)bh*DH*SEQ;
  int q0 = blockIdx.x*128 + w*32;   // this wave's 32 Q rows

  // Q as MFMA B-operand: col(q)=lr, k(d)=lh*8..
  bf16x8 qf[2][2];
  #pragma unroll
  for (int qt=0;qt<2;qt++)
    #pragma unroll
    for (int kd=0;kd<2;kd++)
      qf[qt][kd] = *(const bf16x8*)&Q[(size_t)(q0 + qt*16 + lr)*DH + kd*32 + lh*8];

  f32x4 o[2][4] = {};
  float mrun[2] = {-3e38f, -3e38f};
  float lrun[2] = {0.f, 0.f};

  // ping-pong K/V fragment buffers (register double-buffer)
  bf16x8 kA[4][2], vA[4][2], kB[4][2], vB[4][2];
  #pragma unroll
  for (int n=0;n<4;n++)
    #pragma unroll
    for (int kd=0;kd<2;kd++){
      kA[n][kd] = *(const bf16x8*)&Kp[(size_t)(n*16+lr)*DH  + kd*32 + lh*8];
      vA[n][kd] = *(const bf16x8*)&Vt[(size_t)(n*16+lr)*SEQ + kd*32 + lh*8];
    }

  auto proc = [&](int kv0, bf16x8 (&kc)[4][2], bf16x8 (&vc)[4][2],
                  bf16x8 (&kn)[4][2], bf16x8 (&vn)[4][2], bool pref){
    // S^T = K Q^T : row=kv (n*16+lh*4+reg), col=q (qt*16+lr)
    f32x4 s[2][4] = {};
    __builtin_amdgcn_s_setprio(1);
    #pragma unroll
    for (int kd=0;kd<2;kd++)
      #pragma unroll
      for (int qt=0;qt<2;qt++)
        #pragma unroll
        for (int n=0;n<4;n++)
          s[qt][n] = __builtin_amdgcn_mfma_f32_16x16x32_bf16(kc[n][kd], qf[qt][kd], s[qt][n], 0,0,0);
    __builtin_amdgcn_s_setprio(0);
    // prefetch next K/V tile into the other reg buffer (hidden under softmax+PV)
    if (pref){
      int nx = kv0 + 64;
      #pragma unroll
      for (int n=0;n<4;n++)
        #pragma unroll
        for (int kd=0;kd<2;kd++){
          kn[n][kd] = *(const bf16x8*)&Kp[(size_t)(nx + n*16 + lr)*DH + kd*32 + lh*8];
          vn[n][kd] = *(const bf16x8*)&Vt[(size_t)(n*16+lr)*SEQ + nx + kd*32 + lh*8];
        }
    }
    // online softmax: per lane, q=lr; kv spread over (n,reg) in-lane + lh lanes
    #pragma unroll
    for (int qt=0;qt<2;qt++){
      float pm = -3e38f;
      #pragma unroll
      for (int n=0;n<4;n++){
        float a = fmaxf(fmaxf(s[qt][n][0], s[qt][n][1]), fmaxf(s[qt][n][2], s[qt][n][3]));
        pm = fmaxf(pm, a);
      }
      pm = fmaxf(pm, __shfl_xor(pm, 16));
      pm = fmaxf(pm, __shfl_xor(pm, 32));
      // defer-max: rescale only when tile max meaningfully exceeds running max
      if (__any(pm > mrun[qt] + 8.f)){
        float mn = fmaxf(mrun[qt], pm);
        float sc = __expf(mrun[qt] - mn);
        mrun[qt] = mn;
        lrun[qt] *= sc;
        #pragma unroll
        for (int reg=0;reg<4;reg++){
          float scq = __shfl(sc, (l & 48) | (lh*4 + reg));  // o rows are q=lh*4+reg
          #pragma unroll
          for (int n=0;n<4;n++) o[qt][n][reg] *= scq;
        }
      }
      float rs = 0.f;
      #pragma unroll
      for (int n=0;n<4;n++)
        #pragma unroll
        for (int reg=0;reg<4;reg++){
          float p = __expf(s[qt][n][reg] - mrun[qt]);
          s[qt][n][reg] = p;
          rs += p;
        }
      rs += __shfl_xor(rs, 16);
      rs += __shfl_xor(rs, 32);
      lrun[qt] += rs;
      // P -> LDS, 8B vector stores: row q=qt*16+lr, cols kv=n*16+lh*4..+3
      #pragma unroll
      for (int n=0;n<4;n++){
        uint2 pk;
        pk.x = pack2bf(s[qt][n][0], s[qt][n][1]);
        pk.y = pack2bf(s[qt][n][2], s[qt][n][3]);
        *(uint2*)&pl[w][qt*16+lr][n*16 + lh*4] = pk;
      }
    }
    // O += P @ V
    #pragma unroll
    for (int kk=0;kk<2;kk++){
      bf16x8 pf[2];
      #pragma unroll
      for (int qt=0;qt<2;qt++)
        pf[qt] = *(const bf16x8*)&pl[w][qt*16+lr][kk*32 + lh*8];
      __builtin_amdgcn_s_setprio(1);
      #pragma unroll
      for (int qt=0;qt<2;qt++)
        #pragma unroll
        for (int n=0;n<4;n++)
          o[qt][n] = __builtin_amdgcn_mfma_f32_16x16x32_bf16(pf[qt], vc[n][kk], o[qt][n], 0,0,0);
      __builtin_amdgcn_s_setprio(0);
    }
  };

  for (int kv0=0; kv0<SEQ; kv0+=128){
    proc(kv0,      kA, vA, kB, vB, true);
    proc(kv0+64,   kB, vB, kA, vA, kv0+128 < SEQ);
  }

  // epilogue: O rows q=lh*4+reg need l from lane lr=q
  #pragma unroll
  for (int qt=0;qt<2;qt++){
    float linv = 1.f / lrun[qt];
    #pragma unroll
    for (int reg=0;reg<4;reg++){
      float lq = __shfl(linv, (l & 48) | (lh*4 + reg));
      #pragma unroll
      for (int n=0;n<4;n++){
        int r = q0 + qt*16 + lh*4 + reg;
        int c = hh*DH + n*16 + lr;
        ao[((size_t)b*SEQ + r)*DIM + c] = f2bf(o[qt][n][reg] * lq);
      }
    }
  }
}

extern "C" void kernel_launch(void* const* d_in, const int* in_sizes, int n_in,
                              void* d_out, int out_size, void* d_ws, size_t ws_size,
                              hipStream_t stream)
{
  const float* x     = (const float*)d_in[0];
  const float* gamma = (const float*)d_in[1];
  const float* beta  = (const float*)d_in[2];
  const float* w_qkv = (const float*)d_in[3];
  const float* w_out = (const float*)d_in[4];
  const float* b_out = (const float*)d_in[5];
  float* out = (float*)d_out;

  bf16* ws  = (bf16*)d_ws;
  bf16* xn  = ws;                                  // 4096*1024
  bf16* wqt = xn  + (size_t)ROWS*DIM;              // 3072*1024
  bf16* wot = wqt + (size_t)NQKV*DIM;              // 1024*1024
  bf16* qb  = wot + (size_t)DIM*DIM;               // 32*2048*64
  bf16* kb  = qb  + (size_t)BATCH*HEADS*SEQ*DH;
  bf16* vtb = kb  + (size_t)BATCH*HEADS*SEQ*DH;
  bf16* ao  = vtb + (size_t)BATCH*HEADS*SEQ*DH;    // 4096*1024

  hipLaunchKernelGGL(ln_kernel, dim3(ROWS), dim3(256), 0, stream, x, gamma, beta, xn);
  hipLaunchKernelGGL(transpose_cast, dim3(NQKV/64, DIM/64), dim3(256), 0, stream, w_qkv, wqt, DIM, NQKV);
  hipLaunchKernelGGL(transpose_cast, dim3(DIM/64,  DIM/64), dim3(256), 0, stream, w_out, wot, DIM, DIM);
  hipLaunchKernelGGL(gemm_bt, dim3(NQKV/128, ROWS/128), dim3(256), 0, stream,
                     xn, wqt, DIM, 0, qb, kb, vtb, (float*)nullptr, (const float*)nullptr);
  hipLaunchKernelGGL(attn_kernel, dim3(SEQ/128, BATCH*HEADS), dim3(256), 0, stream, qb, kb, vtb, ao);
  hipLaunchKernelGGL(gemm_bt, dim3(DIM/128, ROWS/128), dim3(256), 0, stream,
                     ao, wot, DIM, 1, (bf16*)nullptr, (bf16*)nullptr, (bf16*)nullptr, out, b_out);
}

// Round 3
// 172.502 us; speedup vs baseline: 1.3269x; 1.2120x over previous
//
#include <hip/hip_runtime.h>
#include <hip/hip_bf16.h>

#define HEADS 16
#define DH 64
#define DIM 1024
#define SEQ 2048
#define BATCH 2
#define ROWS (BATCH*SEQ)      // 4096
#define NQKV (3*DIM)          // 3072
#define NKVT (SEQ/64)         // 32 kv tiles per bh

typedef __attribute__((ext_vector_type(8))) short bf16x8;
typedef __attribute__((ext_vector_type(4))) float f32x4;
typedef __hip_bfloat16 bf16;

static __device__ __forceinline__ bf16 f2bf(float v){ return __float2bfloat16(v); }

static __device__ __forceinline__ unsigned pack2bf(float a, float b){
  bf16 x = f2bf(a), y = f2bf(b);
  unsigned short ux = *(unsigned short*)&x, uy = *(unsigned short*)&y;
  return (unsigned)ux | ((unsigned)uy << 16);
}

static __device__ __forceinline__ void gload16(const void* g, void* lds){
  __builtin_amdgcn_global_load_lds((const __attribute__((address_space(1))) void*)g,
                                   (__attribute__((address_space(3))) void*)lds, 16, 0, 0);
}

// ---------------- LayerNorm: fp32 in -> bf16 out ----------------
__global__ __launch_bounds__(256) void ln_kernel(const float* __restrict__ x,
    const float* __restrict__ gamma, const float* __restrict__ beta,
    bf16* __restrict__ xn)
{
  int row = blockIdx.x;
  int tid = threadIdx.x;
  float4 v = ((const float4*)(x + (size_t)row*DIM))[tid];
  float s  = v.x+v.y+v.z+v.w;
  float ss = v.x*v.x+v.y*v.y+v.z*v.z+v.w*v.w;
  #pragma unroll
  for (int m=1;m<64;m<<=1){ s += __shfl_xor(s,m); ss += __shfl_xor(ss,m); }
  __shared__ float red[8];
  int wid = tid>>6;
  if ((tid&63)==0){ red[wid]=s; red[4+wid]=ss; }
  __syncthreads();
  s  = red[0]+red[1]+red[2]+red[3];
  ss = red[4]+red[5]+red[6]+red[7];
  float mu  = s*(1.0f/DIM);
  float var = ss*(1.0f/DIM) - mu*mu;
  float inv = rsqrtf(var + 1e-5f);
  float4 g  = ((const float4*)gamma)[tid];
  float4 bb = ((const float4*)beta)[tid];
  __align__(8) bf16 o[4];
  o[0]=f2bf((v.x-mu)*inv*g.x+bb.x);
  o[1]=f2bf((v.y-mu)*inv*g.y+bb.y);
  o[2]=f2bf((v.z-mu)*inv*g.z+bb.z);
  o[3]=f2bf((v.w-mu)*inv*g.w+bb.w);
  *(uint2*)&xn[(size_t)row*DIM + tid*4] = *(const uint2*)o;
}

// ---------------- transpose + cast: in[R][C] fp32 -> out[C][R] bf16 ----------------
__global__ __launch_bounds__(256) void transpose_cast(const float* __restrict__ in,
    bf16* __restrict__ out, int R, int C)
{
  __shared__ __align__(16) bf16 t[64][72];
  int c0 = blockIdx.x*64, r0 = blockIdx.y*64;
  int tid = threadIdx.x;
  int row = tid>>2;
  int cq  = (tid&3)*16;
  #pragma unroll
  for (int j=0;j<4;j++){
    float4 v = *(const float4*)&in[(size_t)(r0+row)*C + c0 + cq + j*4];
    t[cq+j*4+0][row] = f2bf(v.x);
    t[cq+j*4+1][row] = f2bf(v.y);
    t[cq+j*4+2][row] = f2bf(v.z);
    t[cq+j*4+3][row] = f2bf(v.w);
  }
  __syncthreads();
  int c = tid>>2; int rq = (tid&3)*16;
  uint4 u0 = *(const uint4*)&t[c][rq];
  uint4 u1 = *(const uint4*)&t[c][rq+8];
  *(uint4*)&out[(size_t)(c0+c)*R + r0 + rq]     = u0;
  *(uint4*)&out[(size_t)(c0+c)*R + r0 + rq + 8] = u1;
}

// ---------------- GEMM: C[M][N] = A[M][K] * Bt[N][K]^T  (m97 structure) ----------------
// mode 0 epilogue: q scaled row-major; K,V stored in per-(bh,tile) 64x64 tiles,
// XOR-pre-swizzled in GLOBAL memory so the attn kernel's linear global_load_lds
// staging yields a bank-conflict-free LDS image (rule 21 / m173 pattern).
__global__ __launch_bounds__(256) void gemm_bt(
    const bf16* __restrict__ A, const bf16* __restrict__ Bt, int K, int mode,
    bf16* __restrict__ qb, bf16* __restrict__ kb, bf16* __restrict__ vtb,
    float* __restrict__ outf, const float* __restrict__ bias)
{
  __shared__ __align__(16) bf16 aL[128*32];
  __shared__ __align__(16) bf16 bL[128*32];
  int tid = threadIdx.x;
  int w = tid>>6, l = tid&63;
  int lr = l&15, lh = l>>4;
  int wr = w>>1, wc = w&1;
  int by = blockIdx.y, bx = blockIdx.x;
  const bf16* Ab = A  + (size_t)(by*128)*K;
  const bf16* Bb = Bt + (size_t)(bx*128)*K;
  int srow = w*32 + (l>>2);
  int skc  = (l&3)*8;
  f32x4 acc[4][4] = {};
  for (int k0=0; k0<K; k0+=32){
    gload16(Ab + (size_t)(srow   )*K + k0 + skc, aL + w*1024      );
    gload16(Ab + (size_t)(srow+16)*K + k0 + skc, aL + w*1024 + 512);
    gload16(Bb + (size_t)(srow   )*K + k0 + skc, bL + w*1024      );
    gload16(Bb + (size_t)(srow+16)*K + k0 + skc, bL + w*1024 + 512);
    __syncthreads();
    bf16x8 af[4], bfr[4];
    #pragma unroll
    for (int m=0;m<4;m++) af[m]  = *(const bf16x8*)&aL[(wr*64 + m*16 + lr)*32 + lh*8];
    #pragma unroll
    for (int n=0;n<4;n++) bfr[n] = *(const bf16x8*)&bL[(wc*64 + n*16 + lr)*32 + lh*8];
    #pragma unroll
    for (int m=0;m<4;m++)
      #pragma unroll
      for (int n=0;n<4;n++)
        acc[m][n] = __builtin_amdgcn_mfma_f32_16x16x32_bf16(af[m], bfr[n], acc[m][n], 0,0,0);
    __syncthreads();
  }
  int rb = by*128 + wr*64, cb = bx*128 + wc*64;
  if (mode == 0){
    #pragma unroll
    for (int m=0;m<4;m++)
      #pragma unroll
      for (int n=0;n<4;n++)
        #pragma unroll
        for (int reg=0;reg<4;reg++){
          int r = rb + m*16 + lh*4 + reg;
          int c = cb + n*16 + lr;
          float v = acc[m][n][reg];
          int b = r >> 11, nn = r & 2047;
          int which = c >> 10, rem = c & 1023;
          int hh = rem >> 6, dd = rem & 63;
          int bh = b*HEADS + hh;
          int kvt = nn >> 6, kvi = nn & 63;
          if (which==0)      qb[((size_t)bh*SEQ + nn)*DH + dd] = f2bf(v*0.125f);
          else if (which==1) kb [(size_t)(bh*NKVT + kvt)*4096 + kvi*64 + (dd  ^ ((kvi&7)<<3))] = f2bf(v);
          else               vtb[(size_t)(bh*NKVT + kvt)*4096 + dd*64  + (kvi ^ ((dd &7)<<3))] = f2bf(v);
        }
  } else {
    #pragma unroll
    for (int m=0;m<4;m++)
      #pragma unroll
      for (int n=0;n<4;n++)
        #pragma unroll
        for (int reg=0;reg<4;reg++){
          int r = rb + m*16 + lh*4 + reg;
          int c = cb + n*16 + lr;
          outf[(size_t)r*DIM + c] = acc[m][n][reg] + bias[c];
        }
  }
}

// ---------------- flash attention v3: LDS-staged K/V, double-buffered pipeline ----------
// K tile in LDS: elem(kv, d) at kv*64 + (d ^ ((kv&7)<<3))   (staged linearly from global)
// V tile in LDS: elem(d, kv) at d*64  + (kv ^ ((d&7)<<3))
__global__ __launch_bounds__(256,2) void attn_kernel(
    const bf16* __restrict__ qb, const bf16* __restrict__ kb,
    const bf16* __restrict__ vtb, bf16* __restrict__ ao)
{
  __shared__ __align__(16) bf16 Kl[2][4096];
  __shared__ __align__(16) bf16 Vl[2][4096];
  __shared__ __align__(16) bf16 Pl[4][2048];
  int tid = threadIdx.x;
  int w = tid>>6, l = tid&63;
  int lr = l&15, lh = l>>4;
  int swz = (lr&7)<<3;
  int bh = blockIdx.y;
  int b  = bh >> 4;
  int hh = bh & 15;
  const bf16* Q  = qb  + (size_t)bh*SEQ*DH;
  const bf16* Kt = kb  + (size_t)bh*NKVT*4096;
  const bf16* Vt = vtb + (size_t)bh*NKVT*4096;
  int q0 = blockIdx.x*128 + w*32;   // this wave's 32 Q rows

  // Q as MFMA B-operand: col(q)=lr, k(d)=lh*8..
  bf16x8 qf[2][2];
  #pragma unroll
  for (int qt=0;qt<2;qt++)
    #pragma unroll
    for (int kd=0;kd<2;kd++)
      qf[qt][kd] = *(const bf16x8*)&Q[(size_t)(q0 + qt*16 + lr)*DH + kd*32 + lh*8];

  f32x4 o[2][4] = {};
  float mrun[2] = {-3e38f, -3e38f};
  float lrun[2] = {0.f, 0.f};

  // prologue: stage tile 0 into buffer 0 (each wave copies 2KB of K and 2KB of V)
  gload16(Kt + w*1024       + l*8, &Kl[0][w*1024      ]);
  gload16(Kt + w*1024 + 512 + l*8, &Kl[0][w*1024 + 512]);
  gload16(Vt + w*1024       + l*8, &Vl[0][w*1024      ]);
  gload16(Vt + w*1024 + 512 + l*8, &Vl[0][w*1024 + 512]);

  for (int t=0; t<NKVT; t++){
    int cur = t&1;
    __syncthreads();                 // drains vmcnt: buf[cur] ready; all waves done reading buf[cur^1]
    if (t+1 < NKVT){                 // issue next tile's loads; they fly under this tile's compute
      const bf16* ks = Kt + (size_t)(t+1)*4096;
      const bf16* vs = Vt + (size_t)(t+1)*4096;
      gload16(ks + w*1024       + l*8, &Kl[cur^1][w*1024      ]);
      gload16(ks + w*1024 + 512 + l*8, &Kl[cur^1][w*1024 + 512]);
      gload16(vs + w*1024       + l*8, &Vl[cur^1][w*1024      ]);
      gload16(vs + w*1024 + 512 + l*8, &Vl[cur^1][w*1024 + 512]);
    }
    // S^T = K Q^T : row=kv (n*16+lh*4+reg), col=q (qt*16+lr)
    f32x4 s[2][4] = {};
    __builtin_amdgcn_s_setprio(1);
    #pragma unroll
    for (int kd=0;kd<2;kd++)
      #pragma unroll
      for (int n=0;n<4;n++){
        bf16x8 kf = *(const bf16x8*)&Kl[cur][(n*16+lr)*64 + ((kd*32+lh*8) ^ swz)];
        #pragma unroll
        for (int qt=0;qt<2;qt++)
          s[qt][n] = __builtin_amdgcn_mfma_f32_16x16x32_bf16(kf, qf[qt][kd], s[qt][n], 0,0,0);
      }
    __builtin_amdgcn_s_setprio(0);
    // online softmax: per lane, q=lr; kv spread over (n,reg) in-lane + lh lanes
    #pragma unroll
    for (int qt=0;qt<2;qt++){
      float pm = -3e38f;
      #pragma unroll
      for (int n=0;n<4;n++){
        float a = fmaxf(fmaxf(s[qt][n][0], s[qt][n][1]), fmaxf(s[qt][n][2], s[qt][n][3]));
        pm = fmaxf(pm, a);
      }
      pm = fmaxf(pm, __shfl_xor(pm, 16));
      pm = fmaxf(pm, __shfl_xor(pm, 32));
      if (__any(pm > mrun[qt] + 8.f)){       // defer-max (T13)
        float mn = fmaxf(mrun[qt], pm);
        float sc = __expf(mrun[qt] - mn);
        mrun[qt] = mn;
        lrun[qt] *= sc;
        #pragma unroll
        for (int reg=0;reg<4;reg++){
          float scq = __shfl(sc, (l & 48) | (lh*4 + reg));  // o rows are q=lh*4+reg
          #pragma unroll
          for (int n=0;n<4;n++) o[qt][n][reg] *= scq;
        }
      }
      float rs = 0.f;
      #pragma unroll
      for (int n=0;n<4;n++)
        #pragma unroll
        for (int reg=0;reg<4;reg++){
          float p = __expf(s[qt][n][reg] - mrun[qt]);
          s[qt][n][reg] = p;
          rs += p;
        }
      rs += __shfl_xor(rs, 16);
      rs += __shfl_xor(rs, 32);
      lrun[qt] += rs;
      // P -> LDS (swizzled, 8B stores): row q=qt*16+lr, cols kv=n*16+lh*4..+3
      #pragma unroll
      for (int n=0;n<4;n++){
        uint2 pk;
        pk.x = pack2bf(s[qt][n][0], s[qt][n][1]);
        pk.y = pack2bf(s[qt][n][2], s[qt][n][3]);
        *(uint2*)&Pl[w][(qt*16+lr)*64 + ((n*16 + lh*4) ^ swz)] = pk;
      }
    }
    // O += P @ V
    #pragma unroll
    for (int kk=0;kk<2;kk++){
      bf16x8 pf[2];
      #pragma unroll
      for (int qt=0;qt<2;qt++)
        pf[qt] = *(const bf16x8*)&Pl[w][(qt*16+lr)*64 + ((kk*32+lh*8) ^ swz)];
      __builtin_amdgcn_s_setprio(1);
      #pragma unroll
      for (int n=0;n<4;n++){
        bf16x8 vf = *(const bf16x8*)&Vl[cur][(n*16+lr)*64 + ((kk*32+lh*8) ^ swz)];
        #pragma unroll
        for (int qt=0;qt<2;qt++)
          o[qt][n] = __builtin_amdgcn_mfma_f32_16x16x32_bf16(pf[qt], vf, o[qt][n], 0,0,0);
      }
      __builtin_amdgcn_s_setprio(0);
    }
  }
  // epilogue: O rows q=lh*4+reg need l from lane lr=q
  #pragma unroll
  for (int qt=0;qt<2;qt++){
    float linv = 1.f / lrun[qt];
    #pragma unroll
    for (int reg=0;reg<4;reg++){
      float lq = __shfl(linv, (l & 48) | (lh*4 + reg));
      #pragma unroll
      for (int n=0;n<4;n++){
        int r = q0 + qt*16 + lh*4 + reg;
        int c = hh*DH + n*16 + lr;
        ao[((size_t)b*SEQ + r)*DIM + c] = f2bf(o[qt][n][reg] * lq);
      }
    }
  }
}

extern "C" void kernel_launch(void* const* d_in, const int* in_sizes, int n_in,
                              void* d_out, int out_size, void* d_ws, size_t ws_size,
                              hipStream_t stream)
{
  const float* x     = (const float*)d_in[0];
  const float* gamma = (const float*)d_in[1];
  const float* beta  = (const float*)d_in[2];
  const float* w_qkv = (const float*)d_in[3];
  const float* w_out = (const float*)d_in[4];
  const float* b_out = (const float*)d_in[5];
  float* out = (float*)d_out;

  bf16* ws  = (bf16*)d_ws;
  bf16* xn  = ws;                                  // 4096*1024
  bf16* wqt = xn  + (size_t)ROWS*DIM;              // 3072*1024
  bf16* wot = wqt + (size_t)NQKV*DIM;              // 1024*1024
  bf16* qb  = wot + (size_t)DIM*DIM;               // 32*2048*64
  bf16* kb  = qb  + (size_t)BATCH*HEADS*SEQ*DH;
  bf16* vtb = kb  + (size_t)BATCH*HEADS*SEQ*DH;
  bf16* ao  = vtb + (size_t)BATCH*HEADS*SEQ*DH;    // 4096*1024

  hipLaunchKernelGGL(ln_kernel, dim3(ROWS), dim3(256), 0, stream, x, gamma, beta, xn);
  hipLaunchKernelGGL(transpose_cast, dim3(NQKV/64, DIM/64), dim3(256), 0, stream, w_qkv, wqt, DIM, NQKV);
  hipLaunchKernelGGL(transpose_cast, dim3(DIM/64,  DIM/64), dim3(256), 0, stream, w_out, wot, DIM, DIM);
  hipLaunchKernelGGL(gemm_bt, dim3(NQKV/128, ROWS/128), dim3(256), 0, stream,
                     xn, wqt, DIM, 0, qb, kb, vtb, (float*)nullptr, (const float*)nullptr);
  hipLaunchKernelGGL(attn_kernel, dim3(SEQ/128, BATCH*HEADS), dim3(256), 0, stream, qb, kb, vtb, ao);
  hipLaunchKernelGGL(gemm_bt, dim3(DIM/128, ROWS/128), dim3(256), 0, stream,
                     ao, wot, DIM, 1, (bf16*)nullptr, (bf16*)nullptr, (bf16*)nullptr, out, b_out);
}

// Round 4
// 165.780 us; speedup vs baseline: 1.3807x; 1.0405x over previous
//
#include <hip/hip_runtime.h>
#include <hip/hip_bf16.h>

#define HEADS 16
#define DH 64
#define DIM 1024
#define SEQ 2048
#define BATCH 2
#define ROWS (BATCH*SEQ)      // 4096
#define NQKV (3*DIM)          // 3072
#define NKVT (SEQ/64)         // 32 kv tiles per bh
#define QSCALE 0.18033688011112042f   // 0.125 * log2(e)

typedef __attribute__((ext_vector_type(8))) short bf16x8;
typedef __attribute__((ext_vector_type(4))) float f32x4;
typedef __hip_bfloat16 bf16;

static __device__ __forceinline__ bf16 f2bf(float v){ return __float2bfloat16(v); }

static __device__ __forceinline__ unsigned pack2bf(float a, float b){
  bf16 x = f2bf(a), y = f2bf(b);
  unsigned short ux = *(unsigned short*)&x, uy = *(unsigned short*)&y;
  return (unsigned)ux | ((unsigned)uy << 16);
}

static __device__ __forceinline__ void gload16(const void* g, void* lds){
  __builtin_amdgcn_global_load_lds((const __attribute__((address_space(1))) void*)g,
                                   (__attribute__((address_space(3))) void*)lds, 16, 0, 0);
}

// ---------------- LayerNorm: fp32 in -> bf16 out ----------------
__global__ __launch_bounds__(256) void ln_kernel(const float* __restrict__ x,
    const float* __restrict__ gamma, const float* __restrict__ beta,
    bf16* __restrict__ xn)
{
  int row = blockIdx.x;
  int tid = threadIdx.x;
  float4 v = ((const float4*)(x + (size_t)row*DIM))[tid];
  float s  = v.x+v.y+v.z+v.w;
  float ss = v.x*v.x+v.y*v.y+v.z*v.z+v.w*v.w;
  #pragma unroll
  for (int m=1;m<64;m<<=1){ s += __shfl_xor(s,m); ss += __shfl_xor(ss,m); }
  __shared__ float red[8];
  int wid = tid>>6;
  if ((tid&63)==0){ red[wid]=s; red[4+wid]=ss; }
  __syncthreads();
  s  = red[0]+red[1]+red[2]+red[3];
  ss = red[4]+red[5]+red[6]+red[7];
  float mu  = s*(1.0f/DIM);
  float var = ss*(1.0f/DIM) - mu*mu;
  float inv = rsqrtf(var + 1e-5f);
  float4 g  = ((const float4*)gamma)[tid];
  float4 bb = ((const float4*)beta)[tid];
  __align__(8) bf16 o[4];
  o[0]=f2bf((v.x-mu)*inv*g.x+bb.x);
  o[1]=f2bf((v.y-mu)*inv*g.y+bb.y);
  o[2]=f2bf((v.z-mu)*inv*g.z+bb.z);
  o[3]=f2bf((v.w-mu)*inv*g.w+bb.w);
  *(uint2*)&xn[(size_t)row*DIM + tid*4] = *(const uint2*)o;
}

// ---------------- transpose + cast: in[R][C] fp32 -> out[C][R] bf16 ----------------
__global__ __launch_bounds__(256) void transpose_cast(const float* __restrict__ in,
    bf16* __restrict__ out, int R, int C)
{
  __shared__ __align__(16) bf16 t[64][72];
  int c0 = blockIdx.x*64, r0 = blockIdx.y*64;
  int tid = threadIdx.x;
  int row = tid>>2;
  int cq  = (tid&3)*16;
  #pragma unroll
  for (int j=0;j<4;j++){
    float4 v = *(const float4*)&in[(size_t)(r0+row)*C + c0 + cq + j*4];
    t[cq+j*4+0][row] = f2bf(v.x);
    t[cq+j*4+1][row] = f2bf(v.y);
    t[cq+j*4+2][row] = f2bf(v.z);
    t[cq+j*4+3][row] = f2bf(v.w);
  }
  __syncthreads();
  int c = tid>>2; int rq = (tid&3)*16;
  uint4 u0 = *(const uint4*)&t[c][rq];
  uint4 u1 = *(const uint4*)&t[c][rq+8];
  *(uint4*)&out[(size_t)(c0+c)*R + r0 + rq]     = u0;
  *(uint4*)&out[(size_t)(c0+c)*R + r0 + rq + 8] = u1;
}

// ---------------- GEMM: C[M][N] = A[M][K] * Bt[N][K]^T  (m97 structure) ----------------
// mode 0 epilogue: q scaled (log2-domain) row-major; K,V stored in per-(bh,tile) 64x64
// tiles, XOR-pre-swizzled in GLOBAL memory so attn's linear global_load_lds staging
// yields a bank-conflict-free LDS image (rule 21 / m173 pattern).
__global__ __launch_bounds__(256) void gemm_bt(
    const bf16* __restrict__ A, const bf16* __restrict__ Bt, int K, int mode,
    bf16* __restrict__ qb, bf16* __restrict__ kb, bf16* __restrict__ vtb,
    float* __restrict__ outf, const float* __restrict__ bias)
{
  __shared__ __align__(16) bf16 aL[128*32];
  __shared__ __align__(16) bf16 bL[128*32];
  int tid = threadIdx.x;
  int w = tid>>6, l = tid&63;
  int lr = l&15, lh = l>>4;
  int wr = w>>1, wc = w&1;
  int by = blockIdx.y, bx = blockIdx.x;
  const bf16* Ab = A  + (size_t)(by*128)*K;
  const bf16* Bb = Bt + (size_t)(bx*128)*K;
  int srow = w*32 + (l>>2);
  int skc  = (l&3)*8;
  f32x4 acc[4][4] = {};
  for (int k0=0; k0<K; k0+=32){
    gload16(Ab + (size_t)(srow   )*K + k0 + skc, aL + w*1024      );
    gload16(Ab + (size_t)(srow+16)*K + k0 + skc, aL + w*1024 + 512);
    gload16(Bb + (size_t)(srow   )*K + k0 + skc, bL + w*1024      );
    gload16(Bb + (size_t)(srow+16)*K + k0 + skc, bL + w*1024 + 512);
    __syncthreads();
    bf16x8 af[4], bfr[4];
    #pragma unroll
    for (int m=0;m<4;m++) af[m]  = *(const bf16x8*)&aL[(wr*64 + m*16 + lr)*32 + lh*8];
    #pragma unroll
    for (int n=0;n<4;n++) bfr[n] = *(const bf16x8*)&bL[(wc*64 + n*16 + lr)*32 + lh*8];
    #pragma unroll
    for (int m=0;m<4;m++)
      #pragma unroll
      for (int n=0;n<4;n++)
        acc[m][n] = __builtin_amdgcn_mfma_f32_16x16x32_bf16(af[m], bfr[n], acc[m][n], 0,0,0);
    __syncthreads();
  }
  int rb = by*128 + wr*64, cb = bx*128 + wc*64;
  if (mode == 0){
    #pragma unroll
    for (int m=0;m<4;m++)
      #pragma unroll
      for (int n=0;n<4;n++)
        #pragma unroll
        for (int reg=0;reg<4;reg++){
          int r = rb + m*16 + lh*4 + reg;
          int c = cb + n*16 + lr;
          float v = acc[m][n][reg];
          int b = r >> 11, nn = r & 2047;
          int which = c >> 10, rem = c & 1023;
          int hh = rem >> 6, dd = rem & 63;
          int bh = b*HEADS + hh;
          int kvt = nn >> 6, kvi = nn & 63;
          if (which==0)      qb[((size_t)bh*SEQ + nn)*DH + dd] = f2bf(v*QSCALE);
          else if (which==1) kb [(size_t)(bh*NKVT + kvt)*4096 + kvi*64 + (dd  ^ ((kvi&7)<<3))] = f2bf(v);
          else               vtb[(size_t)(bh*NKVT + kvt)*4096 + dd*64  + (kvi ^ ((dd &7)<<3))] = f2bf(v);
        }
  } else {
    #pragma unroll
    for (int m=0;m<4;m++)
      #pragma unroll
      for (int n=0;n<4;n++)
        #pragma unroll
        for (int reg=0;reg<4;reg++){
          int r = rb + m*16 + lh*4 + reg;
          int c = cb + n*16 + lr;
          outf[(size_t)r*DIM + c] = acc[m][n][reg] + bias[c];
        }
  }
}

// ---------------- flash attention v4: 16 Q rows/wave, exp2 softmax, LDS dbuf K/V ------
// K tile in LDS: elem(kv, d) at kv*64 + (d ^ ((kv&7)<<3))   (staged linearly from global)
// V tile in LDS: elem(d, kv) at d*64  + (kv ^ ((d&7)<<3))
__global__ __launch_bounds__(256,4) void attn_kernel(
    const bf16* __restrict__ qb, const bf16* __restrict__ kb,
    const bf16* __restrict__ vtb, bf16* __restrict__ ao)
{
  __shared__ __align__(16) bf16 Kl[2][4096];
  __shared__ __align__(16) bf16 Vl[2][4096];
  __shared__ __align__(16) bf16 Pl[4][1024];
  int tid = threadIdx.x;
  int w = tid>>6, l = tid&63;
  int lr = l&15, lh = l>>4;
  int swz = (lr&7)<<3;
  int bh = blockIdx.y;
  int b  = bh >> 4;
  int hh = bh & 15;
  const bf16* Q  = qb  + (size_t)bh*SEQ*DH;
  const bf16* Kt = kb  + (size_t)bh*NKVT*4096;
  const bf16* Vt = vtb + (size_t)bh*NKVT*4096;
  int q0 = blockIdx.x*64 + w*16;   // this wave's 16 Q rows

  // Q as MFMA B-operand: col(q)=lr, k(d)=lh*8..
  bf16x8 qf[2];
  #pragma unroll
  for (int kd=0;kd<2;kd++)
    qf[kd] = *(const bf16x8*)&Q[(size_t)(q0 + lr)*DH + kd*32 + lh*8];

  f32x4 o[4] = {};
  float mrun = -3e38f;
  float lrun = 0.f;

  // prologue: stage tile 0 into buffer 0 (each wave copies 2KB of K and 2KB of V)
  gload16(Kt + w*1024       + l*8, &Kl[0][w*1024      ]);
  gload16(Kt + w*1024 + 512 + l*8, &Kl[0][w*1024 + 512]);
  gload16(Vt + w*1024       + l*8, &Vl[0][w*1024      ]);
  gload16(Vt + w*1024 + 512 + l*8, &Vl[0][w*1024 + 512]);

  for (int t=0; t<NKVT; t++){
    int cur = t&1;
    __syncthreads();                 // buf[cur] ready; all waves done reading buf[cur^1]
    if (t+1 < NKVT){                 // issue next tile's loads; they fly under compute
      const bf16* ks = Kt + (size_t)(t+1)*4096;
      const bf16* vs = Vt + (size_t)(t+1)*4096;
      gload16(ks + w*1024       + l*8, &Kl[cur^1][w*1024      ]);
      gload16(ks + w*1024 + 512 + l*8, &Kl[cur^1][w*1024 + 512]);
      gload16(vs + w*1024       + l*8, &Vl[cur^1][w*1024      ]);
      gload16(vs + w*1024 + 512 + l*8, &Vl[cur^1][w*1024 + 512]);
    }
    // S^T = K Q^T : row=kv (n*16+lh*4+reg), col=q (lr). Scores are in log2 domain.
    f32x4 s[4] = {};
    __builtin_amdgcn_s_setprio(1);
    #pragma unroll
    for (int kd=0;kd<2;kd++)
      #pragma unroll
      for (int n=0;n<4;n++){
        bf16x8 kf = *(const bf16x8*)&Kl[cur][(n*16+lr)*64 + ((kd*32+lh*8) ^ swz)];
        s[n] = __builtin_amdgcn_mfma_f32_16x16x32_bf16(kf, qf[kd], s[n], 0,0,0);
      }
    __builtin_amdgcn_s_setprio(0);
    // online softmax in log2 domain: per lane q=lr; kv over (n,reg) in-lane + lh lanes
    float pm = -3e38f;
    #pragma unroll
    for (int n=0;n<4;n++){
      float a = fmaxf(fmaxf(s[n][0], s[n][1]), fmaxf(s[n][2], s[n][3]));
      pm = fmaxf(pm, a);
    }
    pm = fmaxf(pm, __shfl_xor(pm, 16));
    pm = fmaxf(pm, __shfl_xor(pm, 32));
    if (__any(pm > mrun + 8.f)){       // defer-max (T13): P bounded by 2^8
      float mn = fmaxf(mrun, pm);
      float sc = __builtin_amdgcn_exp2f(mrun - mn);
      mrun = mn;
      lrun *= sc;
      #pragma unroll
      for (int reg=0;reg<4;reg++){
        float scq = __shfl(sc, (l & 48) | (lh*4 + reg));  // o rows are q=lh*4+reg
        #pragma unroll
        for (int n=0;n<4;n++) o[n][reg] *= scq;
      }
    }
    float rs = 0.f;
    #pragma unroll
    for (int n=0;n<4;n++)
      #pragma unroll
      for (int reg=0;reg<4;reg++){
        float p = __builtin_amdgcn_exp2f(s[n][reg] - mrun);
        s[n][reg] = p;
        rs += p;
      }
    rs += __shfl_xor(rs, 16);
    rs += __shfl_xor(rs, 32);
    lrun += rs;
    // P -> LDS (swizzled, 8B stores): row q=lr, cols kv=n*16+lh*4..+3
    #pragma unroll
    for (int n=0;n<4;n++){
      uint2 pk;
      pk.x = pack2bf(s[n][0], s[n][1]);
      pk.y = pack2bf(s[n][2], s[n][3]);
      *(uint2*)&Pl[w][lr*64 + ((n*16 + lh*4) ^ swz)] = pk;
    }
    // O += P @ V
    #pragma unroll
    for (int kk=0;kk<2;kk++){
      bf16x8 pf = *(const bf16x8*)&Pl[w][lr*64 + ((kk*32+lh*8) ^ swz)];
      __builtin_amdgcn_s_setprio(1);
      #pragma unroll
      for (int n=0;n<4;n++){
        bf16x8 vf = *(const bf16x8*)&Vl[cur][(n*16+lr)*64 + ((kk*32+lh*8) ^ swz)];
        o[n] = __builtin_amdgcn_mfma_f32_16x16x32_bf16(pf, vf, o[n], 0,0,0);
      }
      __builtin_amdgcn_s_setprio(0);
    }
  }
  // epilogue: O rows q=lh*4+reg pull 1/lrun from lane with lr=q (lrun uniform over lh)
  float linv = 1.f / lrun;
  #pragma unroll
  for (int reg=0;reg<4;reg++){
    float lq = __shfl(linv, (l & 48) | (lh*4 + reg));
    #pragma unroll
    for (int n=0;n<4;n++){
      int r = q0 + lh*4 + reg;
      int c = hh*DH + n*16 + lr;
      ao[((size_t)b*SEQ + r)*DIM + c] = f2bf(o[n][reg] * lq);
    }
  }
}

extern "C" void kernel_launch(void* const* d_in, const int* in_sizes, int n_in,
                              void* d_out, int out_size, void* d_ws, size_t ws_size,
                              hipStream_t stream)
{
  const float* x     = (const float*)d_in[0];
  const float* gamma = (const float*)d_in[1];
  const float* beta  = (const float*)d_in[2];
  const float* w_qkv = (const float*)d_in[3];
  const float* w_out = (const float*)d_in[4];
  const float* b_out = (const float*)d_in[5];
  float* out = (float*)d_out;

  bf16* ws  = (bf16*)d_ws;
  bf16* xn  = ws;                                  // 4096*1024
  bf16* wqt = xn  + (size_t)ROWS*DIM;              // 3072*1024
  bf16* wot = wqt + (size_t)NQKV*DIM;              // 1024*1024
  bf16* qb  = wot + (size_t)DIM*DIM;               // 32*2048*64
  bf16* kb  = qb  + (size_t)BATCH*HEADS*SEQ*DH;
  bf16* vtb = kb  + (size_t)BATCH*HEADS*SEQ*DH;
  bf16* ao  = vtb + (size_t)BATCH*HEADS*SEQ*DH;    // 4096*1024

  hipLaunchKernelGGL(ln_kernel, dim3(ROWS), dim3(256), 0, stream, x, gamma, beta, xn);
  hipLaunchKernelGGL(transpose_cast, dim3(NQKV/64, DIM/64), dim3(256), 0, stream, w_qkv, wqt, DIM, NQKV);
  hipLaunchKernelGGL(transpose_cast, dim3(DIM/64,  DIM/64), dim3(256), 0, stream, w_out, wot, DIM, DIM);
  hipLaunchKernelGGL(gemm_bt, dim3(NQKV/128, ROWS/128), dim3(256), 0, stream,
                     xn, wqt, DIM, 0, qb, kb, vtb, (float*)nullptr, (const float*)nullptr);
  hipLaunchKernelGGL(attn_kernel, dim3(SEQ/64, BATCH*HEADS), dim3(256), 0, stream, qb, kb, vtb, ao);
  hipLaunchKernelGGL(gemm_bt, dim3(DIM/128, ROWS/128), dim3(256), 0, stream,
                     ao, wot, DIM, 1, (bf16*)nullptr, (bf16*)nullptr, (bf16*)nullptr, out, b_out);
}